// Round 4
// baseline (77.568 us; speedup 1.0000x reference)
//
#include <hip/hip_runtime.h>

// NLM smoothing: x[B=8, H=256, W=256, C=8] fp32, K=5, sigma=1, h=1, reflect pad.
// Block = 256 threads computes a 32x32 pixel tile; each thread owns FOUR
// vertically adjacent pixels (4x1 register blocking): the 8-row x 5-col padded
// window is loaded once and feeds all four pixels (20 b128/pixel vs 50 naive).
// Distance rewrite: d = |c|^2 + |p|^2 - 2 c.p with |p|^2 precomputed into an
// LDS plane at staging -> 8-fma dot instead of 8 sub + 8 fma per contrib.
// Spatial gaussian exp(-(dr^2+dc^2)/2) folded into 6 compile-time constants.
// gk normalization cancels in w/sum(w).

#define BATCH 8
#define NX 256
#define NY 256
#define TSJ 32
#define TSI 32
#define LW (TSJ + 4)          // 36
#define LH (TSI + 4)          // 36
#define NPIX (LW * LH)        // 1296

__device__ __forceinline__ int reflect_idx(int v) {
    // valid for v in [-2, 257] with N=256
    if (v < 0) v = -v;
    if (v > NY - 1) v = 2 * (NY - 1) - v;
    return v;
}

__global__ __launch_bounds__(256) void nlm_kernel(const float4* __restrict__ xv,
                                                  float4* __restrict__ ov) {
    __shared__ float4 t0[NPIX];   // channels 0-3
    __shared__ float4 t1[NPIX];   // channels 4-7
    __shared__ float  ppl[NPIX];  // |pixel|^2 over all 8 channels

    const int t = threadIdx.x;
    const int bj0 = blockIdx.x * TSJ;
    const int bi0 = blockIdx.y * TSI;
    const int bbase = blockIdx.z * (NX * NY);

    // ---- stage tile (reflect halo) + |p|^2 plane ----
#pragma unroll
    for (int s0 = 0; s0 < NPIX; s0 += 256) {
        const int p = s0 + t;
        if (p < NPIX) {
            const int lr = p / LW;
            const int lc = p - lr * LW;
            const int gi = reflect_idx(bi0 + lr - 2);
            const int gj = reflect_idx(bj0 + lc - 2);
            const int g = (bbase + gi * NY + gj) * 2;
            const float4 a = xv[g];
            const float4 b = xv[g + 1];
            t0[p] = a;
            t1[p] = b;
            ppl[p] = a.x * a.x + a.y * a.y + a.z * a.z + a.w * a.w
                   + b.x * b.x + b.y * b.y + b.z * b.z + b.w * b.w;
        }
    }
    __syncthreads();

    // ---- per-thread: 4 vertical pixels at tile rows i0..i0+3, col lj ----
    const int lj = t & 31;
    const int i0 = (t >> 5) * 4;

    const int cpix0 = (i0 + 2) * LW + (lj + 2);
    float4 c0[4], c1[4];
    float nck[4];
#pragma unroll
    for (int k = 0; k < 4; ++k) {
        c0[k] = t0[cpix0 + k * LW];
        c1[k] = t1[cpix0 + k * LW];
        nck[k] = -ppl[cpix0 + k * LW];
    }

    float4 a0[4], a1[4];
    float ws[4];
#pragma unroll
    for (int k = 0; k < 4; ++k) {
        a0[k] = make_float4(0.f, 0.f, 0.f, 0.f);
        a1[k] = make_float4(0.f, 0.f, 0.f, 0.f);
        ws[k] = 0.f;
    }

    // spatial constants e^{-(dr^2+dc^2)/2}, indexed by dr^2+dc^2 in {0,1,2,4,5,8}
    const float SC0 = 1.0f, SC1 = 0.60653065971f, SC2 = 0.36787944117f,
                SC4 = 0.13533528323f, SC5 = 0.08208499862f, SC8 = 0.01831563889f;

    const int rbase = i0 * LW + lj;  // padded (row i0, col lj) = top-left of pixel0's window

#pragma unroll
    for (int r = 0; r < 8; ++r) {    // padded rows i0 .. i0+7
#pragma unroll
        for (int c = 0; c < 5; ++c) {
            const int pix = rbase + r * LW + c;   // immediate offsets from rbase
            const float4 p0 = t0[pix];
            const float4 p1 = t1[pix];
            const float pp = ppl[pix];
#pragma unroll
            for (int k = 0; k < 4; ++k) {
                if (r >= k && r <= k + 4) {       // pixel k window: rows k..k+4
                    const int dr = r - k - 2;
                    const int dc = c - 2;
                    const int s2 = dr * dr + dc * dc;
                    const float sc = (s2 == 0) ? SC0 : (s2 == 1) ? SC1 :
                                     (s2 == 2) ? SC2 : (s2 == 4) ? SC4 :
                                     (s2 == 5) ? SC5 : SC8;
                    const float dot =
                        p0.x * c0[k].x + p0.y * c0[k].y + p0.z * c0[k].z + p0.w * c0[k].w +
                        p1.x * c1[k].x + p1.y * c1[k].y + p1.z * c1[k].z + p1.w * c1[k].w;
                    // w = sc * exp(-(|c|^2 + |p|^2 - 2 dot))
                    const float w = sc * __expf(fmaf(2.f, dot, nck[k] - pp));
                    a0[k].x += w * p0.x; a0[k].y += w * p0.y;
                    a0[k].z += w * p0.z; a0[k].w += w * p0.w;
                    a1[k].x += w * p1.x; a1[k].y += w * p1.y;
                    a1[k].z += w * p1.z; a1[k].w += w * p1.w;
                    ws[k] += w;
                }
            }
        }
    }

#pragma unroll
    for (int k = 0; k < 4; ++k) {
        const float inv = 1.0f / ws[k];
        float4 o0, o1;
        o0.x = a0[k].x * inv; o0.y = a0[k].y * inv;
        o0.z = a0[k].z * inv; o0.w = a0[k].w * inv;
        o1.x = a1[k].x * inv; o1.y = a1[k].y * inv;
        o1.z = a1[k].z * inv; o1.w = a1[k].w * inv;
        const int o = (bbase + (bi0 + i0 + k) * NY + (bj0 + lj)) * 2;
        ov[o] = o0;
        ov[o + 1] = o1;
    }
}

extern "C" void kernel_launch(void* const* d_in, const int* in_sizes, int n_in,
                              void* d_out, int out_size, void* d_ws, size_t ws_size,
                              hipStream_t stream) {
    const float4* x = (const float4*)d_in[0];
    float4* out = (float4*)d_out;
    dim3 grid(NY / TSJ, NX / TSI, BATCH);  // 8 x 8 x 8 = 512 blocks
    nlm_kernel<<<grid, 256, 0, stream>>>(x, out);
}